// Round 8
// baseline (445.907 us; speedup 1.0000x reference)
//
#include <hip/hip_runtime.h>
#include <math.h>

#define BB 4
#define NN 6000
#define BN (BB*NN)      // 24000
#define SS 48
#define PQ (SS*SS)      // 2304
#define TT 550
#define HH 128

#define TPQ 128         // pq tile
#define TTILE 64        // t tile
#define NTILES 9        // ceil(550/64)
#define KT 16           // k chunk
#define SPLITK 12
#define CAP2 BN         // per-tile list capacity
#define MLP_E 64        // electrons per MLP block

__device__ __constant__ float kINV_2PI = 1.0f / (2.0f * 3.14159f);
__device__ __constant__ float kGAUSS_NORM = 0.3989422804f;
#define LOG2E 1.4426950408889634f

__device__ __forceinline__ float fexp2(float x) { return __builtin_amdgcn_exp2f(x); }

// ---------------- Kernel 1: batched MLP -> resp[bn] ----------------
__global__ __launch_bounds__(256) void mlp_kernel(
    const float* __restrict__ si, const float* __restrict__ mask,
    const float* __restrict__ W1, const float* __restrict__ b1,
    const float* __restrict__ W2, const float* __restrict__ b2,
    const float* __restrict__ W3, const float* __restrict__ b3,
    float* __restrict__ resp)
{
  __shared__ float sW2[HH * HH];          // 64 KB
  __shared__ float sh1T[HH][MLP_E];       // 32 KB, [i][e]
  __shared__ float sW1[2 * HH];
  __shared__ float sb1[HH], sb2[HH], sW3[HH];
  int tid = threadIdx.x;
  for (int i = tid * 4; i < HH * HH; i += 1024)
    *(float4*)&sW2[i] = *(const float4*)&W2[i];
  if (tid < 2 * HH) sW1[tid] = W1[tid];
  if (tid < HH) { sb1[tid] = b1[tid]; sb2[tid] = b2[tid]; sW3[tid] = W3[tid]; }
  int e0 = blockIdx.x * MLP_E;
  int e = tid & 63;
  float x0 = si[2 * (e0 + e)], x1 = si[2 * (e0 + e) + 1];
  __syncthreads();
  int jb = (tid >> 6) * 32;
  #pragma unroll
  for (int jj = 0; jj < 32; ++jj) {
    int j = jb + jj;
    sh1T[j][e] = fmaxf(x0 * sW1[j] + x1 * sW1[HH + j] + sb1[j], 0.0f);
  }
  __syncthreads();
  int c4 = (tid & 31) * 4;
  int eh = tid >> 5;  // 0..7
  float acc[8][4] = {};
  for (int i = 0; i < HH; ++i) {
    float4 w  = *(const float4*)&sW2[i * HH + c4];
    float4 ha = *(const float4*)&sh1T[i][eh * 8];
    float4 hb = *(const float4*)&sh1T[i][eh * 8 + 4];
    float hv[8] = {ha.x, ha.y, ha.z, ha.w, hb.x, hb.y, hb.z, hb.w};
    #pragma unroll
    for (int ee = 0; ee < 8; ++ee) {
      acc[ee][0] += hv[ee] * w.x; acc[ee][1] += hv[ee] * w.y;
      acc[ee][2] += hv[ee] * w.z; acc[ee][3] += hv[ee] * w.w;
    }
  }
  float outp[8];
  #pragma unroll
  for (int ee = 0; ee < 8; ++ee) {
    float sacc = 0.0f;
    #pragma unroll
    for (int cc = 0; cc < 4; ++cc)
      sacc += fmaxf(acc[ee][cc] + sb2[c4 + cc], 0.0f) * sW3[c4 + cc];
    outp[ee] = sacc;
  }
  #pragma unroll
  for (int off = 1; off < 32; off <<= 1)
    #pragma unroll
    for (int ee = 0; ee < 8; ++ee)
      outp[ee] += __shfl_xor(outp[ee], off);
  if ((tid & 31) == 0) {
    float b3v = b3[0];
    #pragma unroll
    for (int ee = 0; ee < 8; ++ee) {
      int eidx = e0 + eh * 8 + ee;
      resp[eidx] = fexp2((outp[ee] + b3v) * LOG2E) * mask[eidx];
    }
  }
}

// ---------------- Kernel 2: GxR[bn][p], Gy[bn][q] ----------------
__global__ __launch_bounds__(256) void gxy_kernel(
    const float* __restrict__ si, const float* __restrict__ sensor,
    const float* __restrict__ resp, const float* __restrict__ el_spread,
    const float* __restrict__ nn_bin_sigma,
    float* __restrict__ GxR, float* __restrict__ Gy)
{
  int idx = blockIdx.x * 256 + threadIdx.x;  // bn*48 + p
  if (idx >= BN * SS) return;
  int bn = idx / SS;
  int p = idx - bn * SS;
  float es = el_spread[0];
  float var = es * es;
  float c = (0.5f / var) * LOG2E;
  float sb = nn_bin_sigma[0];
  float bs = sb * sb;
  float tscale = kGAUSS_NORM / sqrtf(bs);
  float lp = sensor[p * SS * 2];
  float x = si[2 * bn], y = si[2 * bn + 1];
  float dx = x - lp, dy = y - lp;
  GxR[idx] = fexp2(-dx * dx * c) * resp[bn] * (kINV_2PI / var) * tscale;
  Gy[idx]  = fexp2(-dy * dy * c);
}

// ---------------- Kernel 3: zero out + counts ----------------
__global__ __launch_bounds__(256) void zero_kernel(
    float* __restrict__ out, int n, int* __restrict__ counts)
{
  int i = blockIdx.x * 256 + threadIdx.x;
  if (i < n) out[i] = 0.0f;
  if (blockIdx.x == 0 && threadIdx.x < 16) counts[threadIdx.x] = 0;
}

// ---------------- Kernel 4: bin electrons (wave-aggregated atomics) ----------
__global__ __launch_bounds__(256) void bin_kernel(
    const float* __restrict__ zpos, const float* __restrict__ nn_bin_sigma,
    int* __restrict__ counts, int* __restrict__ kidx, float* __restrict__ kz)
{
  int bn = blockIdx.x * 256 + threadIdx.x;
  if (bn >= BN) return;  // BN % 64 == 0: whole waves exit together
  float s = nn_bin_sigma[0];
  float bs = s * s;
  float W = ceilf(sqrtf(128.0f * bs));  // drop terms suppressed by <= e^-64
  float z = zpos[bn];
  int jlo = (int)floorf((z - W) * (1.0f / TTILE));
  int jhi = (int)floorf((z + W) * (1.0f / TTILE));
  jlo = jlo < 0 ? 0 : jlo;
  jhi = jhi > NTILES - 1 ? NTILES - 1 : jhi;
  int lane = threadIdx.x & 63;
  for (int j = 0; j < NTILES; ++j) {
    bool c = (j >= jlo) && (j <= jhi);
    unsigned long long m = __ballot(c);
    if (m == 0ull) continue;
    int leader = __ffsll((unsigned long long)m) - 1;
    int base = 0;
    if (lane == leader) base = atomicAdd(&counts[j], __popcll(m));
    base = __shfl(base, leader);
    if (c) {
      int slot = base + __popcll(m & ((1ull << lane) - 1ull));
      kidx[j * CAP2 + slot] = bn;
      kz[j * CAP2 + slot] = z;
    }
  }
}

// ---------------- Kernel 5: tiled contraction, 128pq x 64t, 8x4 micro --------
// A-staging: 2 passes, each thread one float4 at [tid>>5 + 8*pass][(tid&31)*4]
// -> byte stride 16 within each 16-lane phase = conflict-free (round-3 pattern).
__global__ __launch_bounds__(256) void gemm_kernel(
    const float* __restrict__ GxR, const float* __restrict__ Gy,
    const int* __restrict__ counts, const int* __restrict__ kidx,
    const float* __restrict__ kz, const float* __restrict__ nn_bin_sigma,
    float* __restrict__ out)
{
  __shared__ __attribute__((aligned(16))) float Asm[KT][TPQ];   // 8 KB
  __shared__ __attribute__((aligned(16))) float Esm[KT][TTILE]; // 4 KB

  int tid = threadIdx.x;
  int pqBase = blockIdx.x * TPQ;
  int tileT = blockIdx.y;
  int tBase = tileT * TTILE;

  float s = nn_bin_sigma[0];
  float c2 = (0.5f * LOG2E) / (s * s);

  int count = counts[tileT];
  int chunks = (count + KT - 1) / KT;
  int bz = blockIdx.z;
  int cpsBase = chunks / SPLITK;
  int rem = chunks - cpsBase * SPLITK;
  int myC = cpsBase + (bz < rem ? 1 : 0);
  if (myC == 0) return;
  int chunk0 = bz * cpsBase + (bz < rem ? bz : rem);
  int k0 = chunk0 * KT;
  int kend = k0 + myC * KT;   // may exceed count; staging guarded by count

  const int* __restrict__ myidx = kidx + tileT * CAP2;
  const float* __restrict__ myz = kz + tileT * CAP2;

  int aR = tid >> 5;          // A staging row (pass 0); +8 for pass 1
  int aC = (tid & 31) * 4;    // A staging col
  int eR = tid >> 4;          // E staging row
  int eC = (tid & 15) * 4;    // E staging col
  int tpq = (tid >> 4) * 8;   // compute pq base
  int tt  = (tid & 15) * 4;   // compute t base

  // precompute p/q decomposition for the 4 staged pq columns (loop-invariant)
  int pqc = pqBase + aC;
  int p0 = pqc / SS,       q0 = pqc - p0 * SS;
  int p1 = (pqc+1) / SS,   q1 = (pqc+1) - p1 * SS;
  int p2 = (pqc+2) / SS,   q2 = (pqc+2) - p2 * SS;
  int p3 = (pqc+3) / SS,   q3 = (pqc+3) - p3 * SS;

  float acc[8][4] = {};

  for (int kc = k0; kc < kend; kc += KT) {
    #pragma unroll
    for (int pass = 0; pass < 2; ++pass) {
      int row = aR + pass * 8;
      int k = kc + row;
      float4 av = make_float4(0.f, 0.f, 0.f, 0.f);
      if (k < count) {
        int idx = myidx[k] * SS;
        av.x = GxR[idx + p0] * Gy[idx + q0];
        av.y = GxR[idx + p1] * Gy[idx + q1];
        av.z = GxR[idx + p2] * Gy[idx + q2];
        av.w = GxR[idx + p3] * Gy[idx + q3];
      }
      *(float4*)&Asm[row][aC] = av;
    }
    {
      int k = kc + eR;
      float4 ev = make_float4(0.f, 0.f, 0.f, 0.f);
      if (k < count) {
        float z = myz[k];
        float d0 = (float)(tBase + eC)     - z;
        float d1 = (float)(tBase + eC + 1) - z;
        float d2 = (float)(tBase + eC + 2) - z;
        float d3 = (float)(tBase + eC + 3) - z;
        ev.x = fexp2(-d0 * d0 * c2);
        ev.y = fexp2(-d1 * d1 * c2);
        ev.z = fexp2(-d2 * d2 * c2);
        ev.w = fexp2(-d3 * d3 * c2);
      }
      *(float4*)&Esm[eR][eC] = ev;
    }
    __syncthreads();
    #pragma unroll
    for (int k2 = 0; k2 < KT; ++k2) {
      float4 a0 = *(const float4*)&Asm[k2][tpq];
      float4 a1 = *(const float4*)&Asm[k2][tpq + 4];
      float4 e4 = *(const float4*)&Esm[k2][tt];
      float aa[8] = {a0.x, a0.y, a0.z, a0.w, a1.x, a1.y, a1.z, a1.w};
      float ee[4] = {e4.x, e4.y, e4.z, e4.w};
      #pragma unroll
      for (int i2 = 0; i2 < 8; ++i2)
        #pragma unroll
        for (int j2 = 0; j2 < 4; ++j2)
          acc[i2][j2] += aa[i2] * ee[j2];
    }
    __syncthreads();
  }

  #pragma unroll
  for (int i = 0; i < 8; ++i) {
    int pq = pqBase + tpq + i;
    #pragma unroll
    for (int j = 0; j < 4; ++j) {
      int t = tBase + tt + j;
      if (t < TT) atomicAdd(&out[pq * TT + t], acc[i][j]);
    }
  }
}

extern "C" void kernel_launch(void* const* d_in, const int* in_sizes, int n_in,
                              void* d_out, int out_size, void* d_ws, size_t ws_size,
                              hipStream_t stream) {
  const float* si     = (const float*)d_in[0];
  const float* zpos   = (const float*)d_in[1];
  const float* mask   = (const float*)d_in[2];
  const float* sensor = (const float*)d_in[3];
  const float* W1     = (const float*)d_in[4];
  const float* b1     = (const float*)d_in[5];
  const float* W2     = (const float*)d_in[6];
  const float* b2     = (const float*)d_in[7];
  const float* W3     = (const float*)d_in[8];
  const float* b3     = (const float*)d_in[9];
  const float* el_spread    = (const float*)d_in[10];
  const float* nn_bin_sigma = (const float*)d_in[11];
  float* out = (float*)d_out;

  float* ws    = (float*)d_ws;
  float* resp  = ws;                          // 24000
  float* GxR   = resp + BN;                   // 24000*48
  float* Gy    = GxR + BN * SS;               // 24000*48
  float* kz    = Gy + BN * SS;                // 9*CAP2
  int*   counts = (int*)(kz + NTILES * CAP2); // 16
  int*   kidx   = counts + 16;                // 9*CAP2

  mlp_kernel<<<BN / MLP_E, 256, 0, stream>>>(si, mask, W1, b1, W2, b2, W3, b3, resp);
  gxy_kernel<<<(BN * SS + 255) / 256, 256, 0, stream>>>(si, sensor, resp, el_spread,
                                                        nn_bin_sigma, GxR, Gy);
  zero_kernel<<<(PQ * TT + 255) / 256, 256, 0, stream>>>(out, PQ * TT, counts);
  bin_kernel<<<(BN + 255) / 256, 256, 0, stream>>>(zpos, nn_bin_sigma, counts, kidx, kz);
  gemm_kernel<<<dim3(PQ / TPQ, NTILES, SPLITK), 256, 0, stream>>>(
      GxR, Gy, counts, kidx, kz, nn_bin_sigma, out);
}

// Round 9
// 359.873 us; speedup vs baseline: 1.2391x; 1.2391x over previous
//
#include <hip/hip_runtime.h>
#include <math.h>

#define BB 4
#define NN 6000
#define BN (BB*NN)      // 24000
#define SS 48
#define PQ (SS*SS)      // 2304
#define TT 550
#define HH 128

#define TPQ 128         // pq tile
#define TTILE 64        // t tile
#define NTILES 9        // ceil(550/64)
#define KT 16           // k chunk
#define SPLITK 8
#define CAP2 BN         // per-tile list capacity
#define MLP_E 64        // electrons per MLP block

__device__ __constant__ float kINV_2PI = 1.0f / (2.0f * 3.14159f);
__device__ __constant__ float kGAUSS_NORM = 0.3989422804f;
#define LOG2E 1.4426950408889634f

__device__ __forceinline__ float fexp2(float x) { return __builtin_amdgcn_exp2f(x); }

// ------------- Kernel 1: MLP + spatial gaussians (merged) -------------
// 64 electrons per block. resp stays in LDS; emits GxR/Gy directly.
__global__ __launch_bounds__(256) void prep_kernel(
    const float* __restrict__ si, const float* __restrict__ mask,
    const float* __restrict__ W1, const float* __restrict__ b1,
    const float* __restrict__ W2, const float* __restrict__ b2,
    const float* __restrict__ W3, const float* __restrict__ b3,
    const float* __restrict__ sensor, const float* __restrict__ el_spread,
    const float* __restrict__ nn_bin_sigma,
    float* __restrict__ GxR, float* __restrict__ Gy)
{
  __shared__ float sW2[HH * HH];          // 64 KB
  __shared__ float sh1T[HH][MLP_E];       // 32 KB, [i][e]
  __shared__ float sW1[2 * HH];
  __shared__ float sb1[HH], sb2[HH], sW3[HH];
  __shared__ float sex[MLP_E], sey[MLP_E], sresp[MLP_E], slin[SS];
  int tid = threadIdx.x;
  for (int i = tid * 4; i < HH * HH; i += 1024)
    *(float4*)&sW2[i] = *(const float4*)&W2[i];
  if (tid < 2 * HH) sW1[tid] = W1[tid];
  if (tid < HH) { sb1[tid] = b1[tid]; sb2[tid] = b2[tid]; sW3[tid] = W3[tid]; }
  if (tid < SS) slin[tid] = sensor[tid * SS * 2];  // lin[p]
  int e0 = blockIdx.x * MLP_E;
  int e = tid & 63;
  float x0 = si[2 * (e0 + e)], x1 = si[2 * (e0 + e) + 1];
  if (tid < MLP_E) { sex[tid] = x0; sey[tid] = x1; }
  __syncthreads();
  // layer 1: each quarter-block covers 32 hidden units for all 64 electrons
  int jb = (tid >> 6) * 32;
  #pragma unroll
  for (int jj = 0; jj < 32; ++jj) {
    int j = jb + jj;
    sh1T[j][e] = fmaxf(x0 * sW1[j] + x1 * sW1[HH + j] + sb1[j], 0.0f);
  }
  __syncthreads();
  // layer 2+3: thread = (e-group of 8) x (4 cols)
  int c4 = (tid & 31) * 4;
  int eh = tid >> 5;  // 0..7
  float acc[8][4] = {};
  for (int i = 0; i < HH; ++i) {
    float4 w  = *(const float4*)&sW2[i * HH + c4];
    float4 ha = *(const float4*)&sh1T[i][eh * 8];
    float4 hb = *(const float4*)&sh1T[i][eh * 8 + 4];
    float hv[8] = {ha.x, ha.y, ha.z, ha.w, hb.x, hb.y, hb.z, hb.w};
    #pragma unroll
    for (int ee = 0; ee < 8; ++ee) {
      acc[ee][0] += hv[ee] * w.x; acc[ee][1] += hv[ee] * w.y;
      acc[ee][2] += hv[ee] * w.z; acc[ee][3] += hv[ee] * w.w;
    }
  }
  float outp[8];
  #pragma unroll
  for (int ee = 0; ee < 8; ++ee) {
    float sacc = 0.0f;
    #pragma unroll
    for (int cc = 0; cc < 4; ++cc)
      sacc += fmaxf(acc[ee][cc] + sb2[c4 + cc], 0.0f) * sW3[c4 + cc];
    outp[ee] = sacc;
  }
  #pragma unroll
  for (int off = 1; off < 32; off <<= 1)
    #pragma unroll
    for (int ee = 0; ee < 8; ++ee)
      outp[ee] += __shfl_xor(outp[ee], off);
  if ((tid & 31) == 0) {
    float b3v = b3[0];
    #pragma unroll
    for (int ee = 0; ee < 8; ++ee) {
      int eidx = e0 + eh * 8 + ee;
      sresp[eh * 8 + ee] = fexp2((outp[ee] + b3v) * LOG2E) * mask[eidx];
    }
  }
  __syncthreads();
  // spatial gaussians for this block's 64 electrons
  float es = el_spread[0];
  float var = es * es;
  float c = (0.5f / var) * LOG2E;
  float sbv = nn_bin_sigma[0];
  float bs = sbv * sbv;
  float amul = (kINV_2PI / var) * (kGAUSS_NORM / sqrtf(bs));
  for (int v = tid; v < MLP_E * SS; v += 256) {
    int ei = v / SS;
    int p = v - ei * SS;
    float lp = slin[p];
    float dx = sex[ei] - lp, dy = sey[ei] - lp;
    GxR[(e0 + ei) * SS + p] = fexp2(-dx * dx * c) * sresp[ei] * amul;
    Gy[(e0 + ei) * SS + p]  = fexp2(-dy * dy * c);
  }
}

// ---------------- Kernel 2: bin electrons (wave-aggregated atomics) ----------
__global__ __launch_bounds__(256) void bin_kernel(
    const float* __restrict__ zpos, const float* __restrict__ nn_bin_sigma,
    int* __restrict__ counts, int* __restrict__ kidx, float* __restrict__ kz)
{
  int bn = blockIdx.x * 256 + threadIdx.x;
  if (bn >= BN) return;  // BN % 64 == 0: whole waves exit together
  float s = nn_bin_sigma[0];
  float bs = s * s;
  float W = ceilf(sqrtf(128.0f * bs));  // drop terms suppressed by <= e^-64
  float z = zpos[bn];
  int jlo = (int)floorf((z - W) * (1.0f / TTILE));
  int jhi = (int)floorf((z + W) * (1.0f / TTILE));
  jlo = jlo < 0 ? 0 : jlo;
  jhi = jhi > NTILES - 1 ? NTILES - 1 : jhi;
  int lane = threadIdx.x & 63;
  for (int j = 0; j < NTILES; ++j) {
    bool c = (j >= jlo) && (j <= jhi);
    unsigned long long m = __ballot(c);
    if (m == 0ull) continue;
    int leader = __ffsll((unsigned long long)m) - 1;
    int base = 0;
    if (lane == leader) base = atomicAdd(&counts[j], __popcll(m));
    base = __shfl(base, leader);
    if (c) {
      int slot = base + __popcll(m & ((1ull << lane) - 1ull));
      kidx[j * CAP2 + slot] = bn;
      kz[j * CAP2 + slot] = z;
    }
  }
}

// ---------------- Kernel 3: tiled contraction -> partials (no atomics) -------
__global__ __launch_bounds__(256) void gemm_kernel(
    const float* __restrict__ GxR, const float* __restrict__ Gy,
    const int* __restrict__ counts, const int* __restrict__ kidx,
    const float* __restrict__ kz, const float* __restrict__ nn_bin_sigma,
    float* __restrict__ part)
{
  __shared__ __attribute__((aligned(16))) float Asm[KT][TPQ];   // 8 KB
  __shared__ __attribute__((aligned(16))) float Esm[KT][TTILE]; // 4 KB

  int tid = threadIdx.x;
  int pqBase = blockIdx.x * TPQ;
  int tileT = blockIdx.y;
  int tBase = tileT * TTILE;
  int bz = blockIdx.z;

  float s = nn_bin_sigma[0];
  float c2 = (0.5f * LOG2E) / (s * s);

  int count = counts[tileT];
  int chunks = (count + KT - 1) / KT;
  int cpsBase = chunks / SPLITK;
  int rem = chunks - cpsBase * SPLITK;
  int myC = cpsBase + (bz < rem ? 1 : 0);
  int chunk0 = bz * cpsBase + (bz < rem ? bz : rem);
  int k0 = chunk0 * KT;
  int kend = k0 + myC * KT;   // may exceed count; staging guarded

  const int* __restrict__ myidx = kidx + tileT * CAP2;
  const float* __restrict__ myz = kz + tileT * CAP2;

  int aR = tid >> 5;          // A staging row (pass 0); +8 for pass 1
  int aC = (tid & 31) * 4;    // A staging col (byte stride 16 -> conflict-free)
  int eR = tid >> 4;          // E staging row
  int eC = (tid & 15) * 4;    // E staging col
  int tpq = (tid >> 4) * 8;   // compute pq base
  int tt  = (tid & 15) * 4;   // compute t base

  int pqc = pqBase + aC;
  int p0 = pqc / SS,       q0 = pqc - p0 * SS;
  int p1 = (pqc+1) / SS,   q1 = (pqc+1) - p1 * SS;
  int p2 = (pqc+2) / SS,   q2 = (pqc+2) - p2 * SS;
  int p3 = (pqc+3) / SS,   q3 = (pqc+3) - p3 * SS;

  float acc[8][4] = {};

  for (int kc = k0; kc < kend; kc += KT) {
    #pragma unroll
    for (int pass = 0; pass < 2; ++pass) {
      int row = aR + pass * 8;
      int k = kc + row;
      float4 av = make_float4(0.f, 0.f, 0.f, 0.f);
      if (k < count) {
        int idx = myidx[k] * SS;
        av.x = GxR[idx + p0] * Gy[idx + q0];
        av.y = GxR[idx + p1] * Gy[idx + q1];
        av.z = GxR[idx + p2] * Gy[idx + q2];
        av.w = GxR[idx + p3] * Gy[idx + q3];
      }
      *(float4*)&Asm[row][aC] = av;
    }
    {
      int k = kc + eR;
      float4 ev = make_float4(0.f, 0.f, 0.f, 0.f);
      if (k < count) {
        float z = myz[k];
        float d0 = (float)(tBase + eC)     - z;
        float d1 = (float)(tBase + eC + 1) - z;
        float d2 = (float)(tBase + eC + 2) - z;
        float d3 = (float)(tBase + eC + 3) - z;
        ev.x = fexp2(-d0 * d0 * c2);
        ev.y = fexp2(-d1 * d1 * c2);
        ev.z = fexp2(-d2 * d2 * c2);
        ev.w = fexp2(-d3 * d3 * c2);
      }
      *(float4*)&Esm[eR][eC] = ev;
    }
    __syncthreads();
    #pragma unroll
    for (int k2 = 0; k2 < KT; ++k2) {
      float4 a0 = *(const float4*)&Asm[k2][tpq];
      float4 a1 = *(const float4*)&Asm[k2][tpq + 4];
      float4 e4 = *(const float4*)&Esm[k2][tt];
      float aa[8] = {a0.x, a0.y, a0.z, a0.w, a1.x, a1.y, a1.z, a1.w};
      float ee[4] = {e4.x, e4.y, e4.z, e4.w};
      #pragma unroll
      for (int i2 = 0; i2 < 8; ++i2)
        #pragma unroll
        for (int j2 = 0; j2 < 4; ++j2)
          acc[i2][j2] += aa[i2] * ee[j2];
    }
    __syncthreads();
  }

  // plain coalesced partial store (written even when myC==0: zeros)
  float* pb = part + ((tileT * SPLITK + bz) * PQ) * TTILE;
  #pragma unroll
  for (int i = 0; i < 8; ++i) {
    int pq = pqBase + tpq + i;
    *(float4*)&pb[pq * TTILE + tt] =
        make_float4(acc[i][0], acc[i][1], acc[i][2], acc[i][3]);
  }
}

// ---------------- Kernel 4: reduce partials -> out ----------------
__global__ __launch_bounds__(256) void reduce_kernel(
    const float* __restrict__ part, float* __restrict__ out)
{
  int i = blockIdx.x * 256 + threadIdx.x;
  if (i >= PQ * TT) return;
  int pq = i / TT;
  int t = i - pq * TT;
  int tileT = t >> 6;
  int tl = t & 63;
  const float* p = part + ((tileT * SPLITK) * PQ + pq) * TTILE + tl;
  float sum = 0.0f;
  #pragma unroll
  for (int s2 = 0; s2 < SPLITK; ++s2)
    sum += p[s2 * (PQ * TTILE)];
  out[i] = sum;
}

extern "C" void kernel_launch(void* const* d_in, const int* in_sizes, int n_in,
                              void* d_out, int out_size, void* d_ws, size_t ws_size,
                              hipStream_t stream) {
  const float* si     = (const float*)d_in[0];
  const float* zpos   = (const float*)d_in[1];
  const float* mask   = (const float*)d_in[2];
  const float* sensor = (const float*)d_in[3];
  const float* W1     = (const float*)d_in[4];
  const float* b1     = (const float*)d_in[5];
  const float* W2     = (const float*)d_in[6];
  const float* b2     = (const float*)d_in[7];
  const float* W3     = (const float*)d_in[8];
  const float* b3     = (const float*)d_in[9];
  const float* el_spread    = (const float*)d_in[10];
  const float* nn_bin_sigma = (const float*)d_in[11];
  float* out = (float*)d_out;

  float* ws    = (float*)d_ws;
  float* part  = ws;                              // 9*8*2304*64 = 10.6M floats
  float* GxR   = part + NTILES * SPLITK * PQ * TTILE;
  float* Gy    = GxR + BN * SS;                   // 24000*48
  float* kz    = Gy + BN * SS;                    // 9*CAP2
  int*   counts = (int*)(kz + NTILES * CAP2);     // 16
  int*   kidx   = counts + 16;                    // 9*CAP2

  hipMemsetAsync(counts, 0, 16 * sizeof(int), stream);
  prep_kernel<<<BN / MLP_E, 256, 0, stream>>>(si, mask, W1, b1, W2, b2, W3, b3,
                                              sensor, el_spread, nn_bin_sigma, GxR, Gy);
  bin_kernel<<<(BN + 255) / 256, 256, 0, stream>>>(zpos, nn_bin_sigma, counts, kidx, kz);
  gemm_kernel<<<dim3(PQ / TPQ, NTILES, SPLITK), 256, 0, stream>>>(
      GxR, Gy, counts, kidx, kz, nn_bin_sigma, part);
  reduce_kernel<<<(PQ * TT + 255) / 256, 256, 0, stream>>>(part, out);
}